// Round 1
// baseline (2067.900 us; speedup 1.0000x reference)
//
#include <hip/hip_runtime.h>
#include <math.h>

#define F0 1433
#define F1 32
#define F2 7

// ---------------- degree / dinv ----------------
__global__ void k_init_deg(float* __restrict__ deg, int N) {
    int i = blockIdx.x * 256 + threadIdx.x;
    if (i < N) deg[i] = 1.0f;   // self-loop contributes 1
}

__global__ void k_count_deg(const int* __restrict__ dst, float* __restrict__ deg, int E) {
    int e = blockIdx.x * 256 + threadIdx.x;
    if (e < E) atomicAdd(&deg[dst[e]], 1.0f);
}

__global__ void k_dinv(float* __restrict__ deg, int N) {
    int i = blockIdx.x * 256 + threadIdx.x;
    if (i < N) deg[i] = rsqrtf(deg[i]);   // deg >= 1 always (self-loops)
}

// ---------------- GEMM1: h1[N,32] = x[N,1433] @ W1[1433,32] ----------------
// Tile: M=64 rows, all 32 cols, K-chunk=64. Block 256 threads.
// Thread tile: 2 rows x 4 cols. LDS x row stride 68 (=64+4) spreads banks for b128 reads.
#define BM 64
#define BK 64
#define XS_LD 68
__global__ __launch_bounds__(256) void k_gemm1(const float* __restrict__ x,
                                               const float* __restrict__ W,
                                               float* __restrict__ h, int N) {
    __shared__ float xs[BM * XS_LD];   // 17408 B
    __shared__ float wsm[BK * F1];     // 8192 B
    const int tid  = threadIdx.x;
    const int row0 = blockIdx.x * BM;
    const int cg   = tid & 7;    // 8 col-groups of 4 cols
    const int r    = tid >> 3;   // 0..31 -> rows r and r+32

    float acc0x = 0.f, acc0y = 0.f, acc0z = 0.f, acc0w = 0.f;
    float acc1x = 0.f, acc1y = 0.f, acc1z = 0.f, acc1w = 0.f;

    for (int k0 = 0; k0 < F0; k0 += BK) {
        // stage x tile [64][64] coalesced
        #pragma unroll
        for (int l = 0; l < 16; ++l) {
            int idx = tid + l * 256;           // 0..4095
            int i = idx >> 6, j = idx & 63;
            int gr = row0 + i, gk = k0 + j;
            float v = 0.f;
            if (gr < N && gk < F0) v = x[(long)gr * F0 + gk];
            xs[i * XS_LD + j] = v;
        }
        // stage W tile [64][32] coalesced
        #pragma unroll
        for (int l = 0; l < 8; ++l) {
            int idx = tid + l * 256;           // 0..2047
            int kk = idx >> 5;
            int gk = k0 + kk;
            wsm[idx] = (gk < F0) ? W[gk * F1 + (idx & 31)] : 0.f;
        }
        __syncthreads();

        #pragma unroll
        for (int kk = 0; kk < BK; kk += 4) {
            float4 xa = *(const float4*)&xs[r * XS_LD + kk];
            float4 xb = *(const float4*)&xs[(r + 32) * XS_LD + kk];
            const float av[4] = {xa.x, xa.y, xa.z, xa.w};
            const float bv[4] = {xb.x, xb.y, xb.z, xb.w};
            #pragma unroll
            for (int u = 0; u < 4; ++u) {
                float4 w = *(const float4*)&wsm[(kk + u) * F1 + cg * 4];
                float a = av[u], b = bv[u];
                acc0x += a * w.x; acc0y += a * w.y; acc0z += a * w.z; acc0w += a * w.w;
                acc1x += b * w.x; acc1y += b * w.y; acc1z += b * w.z; acc1w += b * w.w;
            }
        }
        __syncthreads();
    }
    int gr0 = row0 + r, gr1 = row0 + r + 32;
    if (gr0 < N) *(float4*)&h[(long)gr0 * F1 + cg * 4] = make_float4(acc0x, acc0y, acc0z, acc0w);
    if (gr1 < N) *(float4*)&h[(long)gr1 * F1 + cg * 4] = make_float4(acc1x, acc1y, acc1z, acc1w);
}

// ---------------- layer-1 aggregation ----------------
// init: agg1 = h1 * dinv^2  (self-loop term; also serves as zero-init)
__global__ void k_selfloop1(const float* __restrict__ h1, const float* __restrict__ dinv,
                            float* __restrict__ agg, int N) {
    int t = blockIdx.x * 256 + threadIdx.x;
    if (t < N * F1) {
        int i = t >> 5;
        float d = dinv[i];
        agg[t] = h1[t] * d * d;
    }
}

// one thread per (edge, feature); 2 edges per wave
__global__ void k_scatter1(const int* __restrict__ src, const int* __restrict__ dst,
                           const float* __restrict__ dinv, const float* __restrict__ h1,
                           float* __restrict__ agg, int E) {
    int t = blockIdx.x * 256 + threadIdx.x;
    int e = t >> 5;
    if (e >= E) return;
    int f = t & 31;
    int s = src[e], d = dst[e];
    float w = dinv[s] * dinv[d];
    atomicAdd(&agg[d * F1 + f], h1[s * F1 + f] * w);
}

// ---------------- fused: ReLU(agg1+b1) @ W2 -> h2 ; out init = h2*dinv^2 ----------------
__global__ __launch_bounds__(256) void k_layer2(const float* __restrict__ agg1,
                                                const float* __restrict__ b1,
                                                const float* __restrict__ W2,
                                                const float* __restrict__ dinv,
                                                float* __restrict__ h2,
                                                float* __restrict__ out, int N) {
    __shared__ float w2s[F1 * F2];
    __shared__ float b1s[F1];
    int tid = threadIdx.x;
    if (tid < F1 * F2) w2s[tid] = W2[tid];
    if (tid < F1) b1s[tid] = b1[tid];
    __syncthreads();
    int i = blockIdx.x * 256 + tid;
    if (i >= N) return;
    float v[F1];
    #pragma unroll
    for (int u = 0; u < 8; ++u) {
        float4 t = *(const float4*)&agg1[(long)i * F1 + u * 4];
        v[u*4+0] = fmaxf(t.x + b1s[u*4+0], 0.f);
        v[u*4+1] = fmaxf(t.y + b1s[u*4+1], 0.f);
        v[u*4+2] = fmaxf(t.z + b1s[u*4+2], 0.f);
        v[u*4+3] = fmaxf(t.w + b1s[u*4+3], 0.f);
    }
    float o[F2] = {0.f, 0.f, 0.f, 0.f, 0.f, 0.f, 0.f};
    #pragma unroll
    for (int k = 0; k < F1; ++k) {
        float a = v[k];
        #pragma unroll
        for (int c = 0; c < F2; ++c) o[c] += a * w2s[k * F2 + c];
    }
    float di = dinv[i];
    float dd = di * di;
    #pragma unroll
    for (int c = 0; c < F2; ++c) {
        h2[(long)i * F2 + c] = o[c];
        out[(long)i * F2 + c] = o[c] * dd;
    }
}

// one thread per (edge, class); 8 lanes/edge (lane 7 idle)
__global__ void k_scatter2(const int* __restrict__ src, const int* __restrict__ dst,
                           const float* __restrict__ dinv, const float* __restrict__ h2,
                           float* __restrict__ out, int E) {
    int t = blockIdx.x * 256 + threadIdx.x;
    int e = t >> 3;
    int c = t & 7;
    if (e >= E || c >= F2) return;
    int s = src[e], d = dst[e];
    float w = dinv[s] * dinv[d];
    atomicAdd(&out[(long)d * F2 + c], h2[(long)s * F2 + c] * w);
}

// ---------------- +b2 then log_softmax, in place ----------------
__global__ void k_logsoftmax(float* __restrict__ out, const float* __restrict__ b2, int N) {
    int i = blockIdx.x * 256 + threadIdx.x;
    if (i >= N) return;
    float v[F2];
    float m = -1e30f;
    #pragma unroll
    for (int c = 0; c < F2; ++c) {
        v[c] = out[(long)i * F2 + c] + b2[c];
        m = fmaxf(m, v[c]);
    }
    float s = 0.f;
    #pragma unroll
    for (int c = 0; c < F2; ++c) s += expf(v[c] - m);
    float l = logf(s);
    #pragma unroll
    for (int c = 0; c < F2; ++c) out[(long)i * F2 + c] = v[c] - m - l;
}

extern "C" void kernel_launch(void* const* d_in, const int* in_sizes, int n_in,
                              void* d_out, int out_size, void* d_ws, size_t ws_size,
                              hipStream_t stream) {
    const float* x  = (const float*)d_in[0];
    const int*   ei = (const int*)d_in[1];
    const float* W1 = (const float*)d_in[2];
    const float* b1 = (const float*)d_in[3];
    const float* W2 = (const float*)d_in[4];
    const float* b2 = (const float*)d_in[5];
    float* out = (float*)d_out;

    const int N = in_sizes[0] / F0;      // 100000
    const int E = in_sizes[1] / 2;       // 3200000
    const int* src = ei;
    const int* dst = ei + E;

    // workspace layout (floats): dinv[N] | h1[N*32] (aliased by h2[N*7]) | agg1[N*32]
    float* ws   = (float*)d_ws;
    size_t o    = 0;
    float* dinv = ws;        o += (size_t)((N + 3) & ~3);
    float* h1   = ws + o;    o += (size_t)N * F1;
    float* agg1 = ws + o;    o += (size_t)N * F1;
    float* h2   = h1;        // h1 is dead after k_scatter1/k_selfloop1

    const int nb_N  = (N + 255) / 256;
    const int nb_E  = (E + 255) / 256;

    k_init_deg  <<<nb_N, 256, 0, stream>>>(dinv, N);
    k_count_deg <<<nb_E, 256, 0, stream>>>(dst, dinv, E);
    k_dinv      <<<nb_N, 256, 0, stream>>>(dinv, N);

    k_gemm1     <<<(N + BM - 1) / BM, 256, 0, stream>>>(x, W1, h1, N);

    k_selfloop1 <<<((size_t)N * F1 + 255) / 256, 256, 0, stream>>>(h1, dinv, agg1, N);
    k_scatter1  <<<((size_t)E * 32 + 255) / 256, 256, 0, stream>>>(src, dst, dinv, h1, agg1, E);

    k_layer2    <<<nb_N, 256, 0, stream>>>(agg1, b1, W2, dinv, h2, out, N);

    k_scatter2  <<<((size_t)E * 8 + 255) / 256, 256, 0, stream>>>(src, dst, dinv, h2, out, E);

    k_logsoftmax<<<nb_N, 256, 0, stream>>>(out, b2, N);
}